// Round 1
// baseline (1651.728 us; speedup 1.0000x reference)
//
#include <hip/hip_runtime.h>
#include <hip/hip_bf16.h>
#include <math.h>

#define NN 200
#define DD 8
#define HH 128
#define NHEAD 4
#define HDIM 32
#define LL 6
#define EE 16384
#define SS 8
#define FFD 512

// ---------------- helpers ----------------

__device__ __forceinline__ float geluf(float x) {
    return 0.5f * x * (1.0f + erff(x * 0.70710678118654752f));
}
__device__ __forceinline__ float softplusf(float x) {
    return (x > 20.0f) ? x : log1pf(expf(x));
}

// block reduction of (a,b) sums over 128 threads (2 waves)
__device__ __forceinline__ void block_reduce2_128(float& a, float& b, float* lds) {
    #pragma unroll
    for (int m = 32; m > 0; m >>= 1) {
        a += __shfl_xor(a, m);
        b += __shfl_xor(b, m);
    }
    int wid = threadIdx.x >> 6;
    int lane = threadIdx.x & 63;
    if (lane == 0) { lds[wid * 2] = a; lds[wid * 2 + 1] = b; }
    __syncthreads();
    a = lds[0] + lds[2];
    b = lds[1] + lds[3];
    __syncthreads();
}

__device__ __forceinline__ float4 shfl_xor4(float4 v, int m) {
    float4 r;
    r.x = __shfl_xor(v.x, m);
    r.y = __shfl_xor(v.y, m);
    r.z = __shfl_xor(v.z, m);
    r.w = __shfl_xor(v.w, m);
    return r;
}

// ---------------- kernels ----------------

// Build G[a][b] = #edges containing both a and b (int atomics: always native)
__global__ void k_buildG(const int* __restrict__ hedges, int* __restrict__ G) {
    int gid = blockIdx.x * 256 + threadIdx.x;   // E*64 total
    if (gid >= EE * 64) return;
    int e = gid >> 6, p = gid & 63;
    int a = hedges[e * SS + (p >> 3)];
    int b = hedges[e * SS + (p & 7)];
    atomicAdd(&G[a * NN + b], 1);
}

// h0 = gelu(LN(x@Wi+bi)) + PE     grid: 200 blocks x 128 threads
__global__ void k_embed(const float* __restrict__ x, const float* __restrict__ Wi,
                        const float* __restrict__ bi, const float* __restrict__ lnig,
                        const float* __restrict__ lnib, float* __restrict__ h) {
    int n = blockIdx.x, j = threadIdx.x;
    __shared__ float red[4];
    float s = bi[j];
    #pragma unroll
    for (int d = 0; d < DD; ++d) s = fmaf(x[n * DD + d], Wi[d * HH + j], s);
    float a = s, b = s * s;
    block_reduce2_128(a, b, red);
    float mean = a * (1.0f / HH);
    float var = b * (1.0f / HH) - mean * mean;
    float v = (s - mean) * rsqrtf(var + 1e-5f) * lnig[j] + lnib[j];
    float ge = geluf(v);
    // positional encoding
    int i2 = (j >> 1) * 2;
    float div = expf((float)i2 * (-9.210340371976184f / 128.0f));
    float ang = (float)n * div;
    float pe = (j & 1) ? cosf(ang) : sinf(ang);
    h[n * HH + j] = ge + pe;
}

// Per-layer node phase 1: hg = G@h ; h1 = LN(h + (hg@Wc)/(8*cnt) + bc) ; Q,K,V = h1@W+b
// grid: 200 blocks x 128 threads
__global__ void k_node1(const float* __restrict__ h, const int* __restrict__ G,
                        const float* __restrict__ Wc, const float* __restrict__ bc,
                        const float* __restrict__ Wq, const float* __restrict__ bq,
                        const float* __restrict__ Wk, const float* __restrict__ bk,
                        const float* __restrict__ Wv, const float* __restrict__ bv,
                        const float* __restrict__ n1g, const float* __restrict__ n1b,
                        float* __restrict__ h1, float* __restrict__ Qo,
                        float* __restrict__ Ko, float* __restrict__ Vo) {
    int n = blockIdx.x, j = threadIdx.x;
    __shared__ float Gs[NN];
    __shared__ float rowbuf[HH];
    __shared__ float red[4];
    for (int m = j; m < NN; m += HH) Gs[m] = (float)G[n * NN + m];
    __syncthreads();
    float cntn = fmaxf(Gs[n], 1.0f);
    float hg = 0.0f;
    #pragma unroll 4
    for (int m = 0; m < NN; ++m) hg = fmaf(Gs[m], h[m * HH + j], hg);
    rowbuf[j] = hg;
    __syncthreads();
    float acc = 0.0f;
    #pragma unroll 4
    for (int k = 0; k < HH; ++k) acc = fmaf(rowbuf[k], Wc[k * HH + j], acc);
    float val = h[n * HH + j] + acc / (8.0f * cntn) + bc[j];
    float a = val, b = val * val;
    block_reduce2_128(a, b, red);   // ends with syncthreads -> rowbuf reuse safe
    float mean = a * (1.0f / HH);
    float var = b * (1.0f / HH) - mean * mean;
    float hv = (val - mean) * rsqrtf(var + 1e-5f) * n1g[j] + n1b[j];
    rowbuf[j] = hv;
    h1[n * HH + j] = hv;
    __syncthreads();
    float q = bq[j], kk = bk[j], vv = bv[j];
    #pragma unroll 4
    for (int k = 0; k < HH; ++k) {
        float hk = rowbuf[k];
        q  = fmaf(hk, Wq[k * HH + j], q);
        kk = fmaf(hk, Wk[k * HH + j], kk);
        vv = fmaf(hk, Wv[k * HH + j], vv);
    }
    Qo[n * HH + j] = q;
    Ko[n * HH + j] = kk;
    Vo[n * HH + j] = vv;
}

// Edge attention. Grid: 512 blocks (256 edge-chunks x 2 head-pairs) x 512 threads.
// Each 16-lane group = one edge: i = lane&7 (member), hb = (lane>>3)&1 (head in pair).
// LDS agg layout: [hb][node][33] (bank-staggered). Block writes one partial slice.
#define AGG_HSTRIDE 6600   // 200*33
__launch_bounds__(512)
__global__ void k_attn(const float* __restrict__ Q, const float* __restrict__ K,
                       const float* __restrict__ V, const int* __restrict__ hedges,
                       float* __restrict__ partials) {
    __shared__ float agg[2 * AGG_HSTRIDE];   // 13200 floats = 52.8 KB
    for (int idx = threadIdx.x; idx < 2 * AGG_HSTRIDE; idx += 512) agg[idx] = 0.0f;
    __syncthreads();

    int tid = threadIdx.x;
    int i = tid & 7;
    int hb = (tid >> 3) & 1;
    int group = tid >> 4;               // 0..31
    int c = blockIdx.x & 255;           // edge chunk
    int hp = blockIdx.x >> 8;           // head pair 0/1
    int head = hp * 2 + hb;
    const float rscale = 0.17677669529663687f;  // 1/sqrt(32)

    for (int t = 0; t < 2; ++t) {
        int e = c * 64 + group * 2 + t;
        int node = hedges[e * SS + i];
        const float4* qp = (const float4*)(Q + node * HH + head * HDIM);
        const float4* kp = (const float4*)(K + node * HH + head * HDIM);
        const float4* vp = (const float4*)(V + node * HH + head * HDIM);
        float4 qv[8], kv[8];
        #pragma unroll
        for (int u = 0; u < 8; ++u) { qv[u] = qp[u]; kv[u] = kp[u]; }
        float sc[8];
        #pragma unroll
        for (int r = 0; r < 8; ++r) {
            float acc = 0.0f;
            #pragma unroll
            for (int u = 0; u < 8; ++u) {
                float4 kr = shfl_xor4(kv[u], r);
                acc += qv[u].x * kr.x + qv[u].y * kr.y + qv[u].z * kr.z + qv[u].w * kr.w;
            }
            sc[r] = acc * rscale;
        }
        float m = sc[0];
        #pragma unroll
        for (int r = 1; r < 8; ++r) m = fmaxf(m, sc[r]);
        float p[8], sum = 0.0f;
        #pragma unroll
        for (int r = 0; r < 8; ++r) { p[r] = __expf(sc[r] - m); sum += p[r]; }
        float inv = 1.0f / sum;
        float4 vv[8], att[8];
        #pragma unroll
        for (int u = 0; u < 8; ++u) { vv[u] = vp[u]; att[u] = make_float4(0.f, 0.f, 0.f, 0.f); }
        #pragma unroll
        for (int r = 0; r < 8; ++r) {
            float pj = p[r] * inv;
            #pragma unroll
            for (int u = 0; u < 8; ++u) {
                float4 vr = shfl_xor4(vv[u], r);
                att[u].x = fmaf(pj, vr.x, att[u].x);
                att[u].y = fmaf(pj, vr.y, att[u].y);
                att[u].z = fmaf(pj, vr.z, att[u].z);
                att[u].w = fmaf(pj, vr.w, att[u].w);
            }
        }
        int abase = hb * AGG_HSTRIDE + node * 33;
        #pragma unroll
        for (int u = 0; u < 8; ++u) {
            atomicAdd(&agg[abase + u * 4 + 0], att[u].x);
            atomicAdd(&agg[abase + u * 4 + 1], att[u].y);
            atomicAdd(&agg[abase + u * 4 + 2], att[u].z);
            atomicAdd(&agg[abase + u * 4 + 3], att[u].w);
        }
    }
    __syncthreads();
    // dump partial: layout per block-slice: idx = n*64 + hh*32 + d  (12800 floats)
    float4* pb = (float4*)(partials + (size_t)hp * (256 * 12800) + (size_t)c * 12800);
    for (int idx4 = tid; idx4 < 3200; idx4 += 512) {
        int idx = idx4 * 4;
        int n = idx >> 6, jj = idx & 63, hh = jj >> 5, d = jj & 31;
        int a = hh * AGG_HSTRIDE + n * 33 + d;
        pb[idx4] = make_float4(agg[a], agg[a + 1], agg[a + 2], agg[a + 3]);
    }
}

// Tail: agg = reduce(partials)/cnt ; h2 = h1 + agg@Wo + bo ; FFN ; h = LN(...)
// grid: 200 blocks x 128 threads
__global__ void k_tail(const float* __restrict__ partials, const int* __restrict__ G,
                       const float* __restrict__ h1,
                       const float* __restrict__ Wo, const float* __restrict__ bo,
                       const float* __restrict__ Wf1, const float* __restrict__ bf1,
                       const float* __restrict__ Wf2, const float* __restrict__ bf2,
                       const float* __restrict__ n2g, const float* __restrict__ n2b,
                       float* __restrict__ h) {
    int n = blockIdx.x, j = threadIdx.x;
    __shared__ float aggs[HH];
    __shared__ float h2s[HH];
    __shared__ float ts[FFD];
    __shared__ float red[4];
    float cntn = fmaxf((float)G[n * NN + n], 1.0f);
    int hp = j >> 6;
    size_t base = (size_t)hp * (256 * 12800) + (size_t)n * 64 + (j & 63);
    float a0 = 0.0f;
    #pragma unroll 8
    for (int b = 0; b < 256; ++b) a0 += partials[base + (size_t)b * 12800];
    aggs[j] = a0 / cntn;
    __syncthreads();
    float h2 = h1[n * HH + j] + bo[j];
    #pragma unroll 4
    for (int k = 0; k < HH; ++k) h2 = fmaf(aggs[k], Wo[k * HH + j], h2);
    h2s[j] = h2;
    __syncthreads();
    #pragma unroll
    for (int c = 0; c < 4; ++c) {
        int f = j + c * HH;
        float tval = bf1[f];
        #pragma unroll 4
        for (int k = 0; k < HH; ++k) tval = fmaf(h2s[k], Wf1[k * FFD + f], tval);
        ts[f] = geluf(tval);
    }
    __syncthreads();
    float o = h2 + bf2[j];
    #pragma unroll 4
    for (int f = 0; f < FFD; ++f) o = fmaf(ts[f], Wf2[f * HH + j], o);
    float a = o, b = o * o;
    block_reduce2_128(a, b, red);
    float mean = a * (1.0f / HH);
    float var = b * (1.0f / HH) - mean * mean;
    h[n * HH + j] = (o - mean) * rsqrtf(var + 1e-5f) * n2g[j] + n2b[j];
}

// Pool + heads + emb. One block, 384 threads.
__global__ void k_final(const float* __restrict__ h,
                        const float* __restrict__ Wh1, const float* __restrict__ bh1,
                        const float* __restrict__ Wh2, const float* __restrict__ bh2,
                        const float* __restrict__ Wh3, const float* __restrict__ bh3,
                        const float* __restrict__ We, const float* __restrict__ be,
                        float* __restrict__ out) {
    __shared__ float gs[384];
    __shared__ float t1s[384];
    __shared__ float t2s[192];
    int t = threadIdx.x;
    if (t < HH) {
        float sm = 0.0f, mx = -3.4e38f;
        for (int n = 0; n < NN; ++n) {
            float v = h[n * HH + t];
            sm += v;
            mx = fmaxf(mx, v);
        }
        gs[t] = sm * (1.0f / NN);
        gs[HH + t] = mx;
        gs[2 * HH + t] = sm;
    }
    __syncthreads();
    {
        int k = t >> 7, o = t & 127;
        float acc = bh1[k * 128 + o];
        for (int i = 0; i < 384; ++i) acc = fmaf(gs[i], Wh1[k * 49152 + i * 128 + o], acc);
        t1s[t] = geluf(acc);
    }
    __syncthreads();
    if (t < 192) {
        int k = t / 64, o = t % 64;
        float acc = bh2[k * 64 + o];
        for (int i = 0; i < 128; ++i) acc = fmaf(t1s[k * 128 + i], Wh2[k * 8192 + i * 64 + o], acc);
        t2s[t] = geluf(acc);
    }
    __syncthreads();
    if (t < 3) {
        float acc = bh3[t];
        for (int i = 0; i < 64; ++i) acc = fmaf(t2s[t * 64 + i], Wh3[t * 64 + i], acc);
        float r;
        if (t == 0)      r = softplusf(acc) + 1.0f;
        else if (t == 1) r = 1.0f / (1.0f + expf(-acc));
        else             r = softplusf(acc);
        out[t] = r;
    }
    if (t < HH) {
        float acc = be[t];
        for (int i = 0; i < 384; ++i) acc = fmaf(gs[i], We[i * 128 + t], acc);
        out[3 + t] = acc;
    }
}

// ---------------- launch ----------------

extern "C" void kernel_launch(void* const* d_in, const int* in_sizes, int n_in,
                              void* d_out, int out_size, void* d_ws, size_t ws_size,
                              hipStream_t stream) {
    const float* x      = (const float*)d_in[0];
    const int*   hedges = (const int*)d_in[1];
    const float* Wi     = (const float*)d_in[2];
    const float* bi     = (const float*)d_in[3];
    const float* lnig   = (const float*)d_in[4];
    const float* lnib   = (const float*)d_in[5];
    const float* Wc     = (const float*)d_in[6];
    const float* bc     = (const float*)d_in[7];
    const float* Wq     = (const float*)d_in[8];
    const float* bq     = (const float*)d_in[9];
    const float* Wk     = (const float*)d_in[10];
    const float* bk     = (const float*)d_in[11];
    const float* Wv     = (const float*)d_in[12];
    const float* bv     = (const float*)d_in[13];
    const float* Wo     = (const float*)d_in[14];
    const float* bo     = (const float*)d_in[15];
    const float* n1g    = (const float*)d_in[16];
    const float* n1b    = (const float*)d_in[17];
    const float* n2g    = (const float*)d_in[18];
    const float* n2b    = (const float*)d_in[19];
    const float* Wf1    = (const float*)d_in[20];
    const float* bf1    = (const float*)d_in[21];
    const float* Wf2    = (const float*)d_in[22];
    const float* bf2    = (const float*)d_in[23];
    const float* Wh1    = (const float*)d_in[24];
    const float* bh1    = (const float*)d_in[25];
    const float* Wh2    = (const float*)d_in[26];
    const float* bh2    = (const float*)d_in[27];
    const float* Wh3    = (const float*)d_in[28];
    const float* bh3    = (const float*)d_in[29];
    const float* We     = (const float*)d_in[30];
    const float* be     = (const float*)d_in[31];

    float* ws = (float*)d_ws;
    float* h        = ws;               // 25600
    float* h1       = ws + 25600;       // 25600
    float* Q        = ws + 51200;       // 25600
    float* K        = ws + 76800;       // 25600
    float* V        = ws + 102400;      // 25600
    int*   G        = (int*)(ws + 128000);   // 40000
    float* partials = ws + 168000;      // 2*256*12800 = 6,553,600

    hipMemsetAsync(G, 0, NN * NN * sizeof(int), stream);
    k_buildG<<<(EE * 64) / 256, 256, 0, stream>>>(hedges, G);
    k_embed<<<NN, HH, 0, stream>>>(x, Wi, bi, lnig, lnib, h);

    for (int l = 0; l < LL; ++l) {
        k_node1<<<NN, HH, 0, stream>>>(h, G,
            Wc + l * HH * HH, bc + l * HH,
            Wq + l * HH * HH, bq + l * HH,
            Wk + l * HH * HH, bk + l * HH,
            Wv + l * HH * HH, bv + l * HH,
            n1g + l * HH, n1b + l * HH,
            h1, Q, K, V);
        k_attn<<<512, 512, 0, stream>>>(Q, K, V, hedges, partials);
        k_tail<<<NN, HH, 0, stream>>>(partials, G, h1,
            Wo + l * HH * HH, bo + l * HH,
            Wf1 + l * HH * FFD, bf1 + l * FFD,
            Wf2 + l * FFD * HH, bf2 + l * HH,
            n2g + l * HH, n2b + l * HH, h);
    }

    k_final<<<1, 384, 0, stream>>>(h, Wh1, bh1, Wh2, bh2, Wh3, bh3, We, be, (float*)d_out);
}

// Round 2
// 1108.645 us; speedup vs baseline: 1.4899x; 1.4899x over previous
//
#include <hip/hip_runtime.h>
#include <hip/hip_bf16.h>
#include <math.h>

#define NN 200
#define DD 8
#define HH 128
#define NHEAD 4
#define HDIM 32
#define LL 6
#define EE 16384
#define SS 8
#define FFD 512

#define WSCALE 1048576.0f       // 2^20 fixed-point scale for attention-weight atomics
#define WNORM  (1.0f/1048576.0f)

// ---------------- helpers ----------------

__device__ __forceinline__ float geluf(float x) {
    return 0.5f * x * (1.0f + erff(x * 0.70710678118654752f));
}
__device__ __forceinline__ float softplusf(float x) {
    return (x > 20.0f) ? x : log1pf(expf(x));
}

// LN mean/var reduce over sv/sv2[128] using first wave; results in mred[0..1]
__device__ __forceinline__ void ln_reduce(const float* sv, const float* sv2, float* mred, int tid) {
    if (tid < 64) {
        float s1 = sv[tid] + sv[tid + 64];
        float s2 = sv2[tid] + sv2[tid + 64];
        #pragma unroll
        for (int m = 32; m > 0; m >>= 1) {
            s1 += __shfl_xor(s1, m);
            s2 += __shfl_xor(s2, m);
        }
        if (tid == 0) { mred[0] = s1 * (1.0f / HH); mred[1] = s2 * (1.0f / HH); }
    }
}

// split-K GEMV pass: out[j] = b[j] + sum_k row[k]*Wm[k][j]   (128x128 weight)
__device__ __forceinline__ void gemv_pass(const float* __restrict__ Wm, const float* __restrict__ bm,
                                          float* __restrict__ outp, const float* row,
                                          float (*psum)[HH], int n, int j, int kq) {
    float pp = 0.0f;
    int k0 = kq * 32;
    #pragma unroll 8
    for (int kk = 0; kk < 32; ++kk) pp = fmaf(row[k0 + kk], Wm[(k0 + kk) * HH + j], pp);
    psum[kq][j] = pp;
    __syncthreads();
    if (kq == 0) outp[n * HH + j] = bm[j] + psum[0][j] + psum[1][j] + psum[2][j] + psum[3][j];
    __syncthreads();
}

// ---------------- kernels ----------------

// Build G[a][b] = #edges containing both a and b
__global__ void k_buildG(const int* __restrict__ hedges, int* __restrict__ G) {
    int gid = blockIdx.x * 256 + threadIdx.x;
    if (gid >= EE * 64) return;
    int e = gid >> 6, p = gid & 63;
    int a = hedges[e * SS + (p >> 3)];
    int b = hedges[e * SS + (p & 7)];
    atomicAdd(&G[a * NN + b], 1);
}

// h0 = gelu(LN(x@Wi+bi)) + PE     grid: 200 x 128
__global__ void k_embed(const float* __restrict__ x, const float* __restrict__ Wi,
                        const float* __restrict__ bi, const float* __restrict__ lnig,
                        const float* __restrict__ lnib, float* __restrict__ h) {
    int n = blockIdx.x, j = threadIdx.x;
    __shared__ float sv[HH], sv2[HH], mred[2];
    float s = bi[j];
    #pragma unroll
    for (int d = 0; d < DD; ++d) s = fmaf(x[n * DD + d], Wi[d * HH + j], s);
    sv[j] = s; sv2[j] = s * s;
    __syncthreads();
    ln_reduce(sv, sv2, mred, j);
    __syncthreads();
    float mean = mred[0], var = mred[1] - mean * mean;
    float v = (s - mean) * rsqrtf(var + 1e-5f) * lnig[j] + lnib[j];
    float ge = geluf(v);
    int i2 = (j >> 1) * 2;
    float div = expf((float)i2 * (-9.210340371976184f / 128.0f));
    float ang = (float)n * div;
    float pe = (j & 1) ? cosf(ang) : sinf(ang);
    h[n * HH + j] = ge + pe;
}

// node phase 1: hg = G@h ; h1 = LN(h + (hg@Wc)/(8*cnt) + bc) ; Q,K,V = h1@W+b
// grid: 200 x 512
__launch_bounds__(512)
__global__ void k_node1(const float* __restrict__ h, const int* __restrict__ G,
                        const float* __restrict__ Wc, const float* __restrict__ bc,
                        const float* __restrict__ Wq, const float* __restrict__ bq,
                        const float* __restrict__ Wk, const float* __restrict__ bk,
                        const float* __restrict__ Wv, const float* __restrict__ bv,
                        const float* __restrict__ n1g, const float* __restrict__ n1b,
                        float* __restrict__ h1, float* __restrict__ Qo,
                        float* __restrict__ Ko, float* __restrict__ Vo) {
    int n = blockIdx.x, tid = threadIdx.x;
    int j = tid & 127, kq = tid >> 7;
    __shared__ float Gs[NN];
    __shared__ float row[HH];
    __shared__ float psum[4][HH];
    __shared__ float sv[HH], sv2[HH], mred[2];
    for (int m = tid; m < NN; m += 512) Gs[m] = (float)G[n * NN + m];
    __syncthreads();
    float cntn = fmaxf(Gs[n], 1.0f);
    // hg = G@h (split over 4 chunks of 50 rows)
    float p = 0.0f;
    {
        int m0 = kq * 50;
        #pragma unroll 5
        for (int mm = 0; mm < 50; ++mm) p = fmaf(Gs[m0 + mm], h[(m0 + mm) * HH + j], p);
    }
    psum[kq][j] = p;
    __syncthreads();
    if (kq == 0) row[j] = psum[0][j] + psum[1][j] + psum[2][j] + psum[3][j];
    __syncthreads();
    // conv GEMV
    p = 0.0f;
    {
        int k0 = kq * 32;
        #pragma unroll 8
        for (int kk = 0; kk < 32; ++kk) p = fmaf(row[k0 + kk], Wc[(k0 + kk) * HH + j], p);
    }
    psum[kq][j] = p;
    __syncthreads();
    float val = 0.0f;
    if (kq == 0) {
        float acc = psum[0][j] + psum[1][j] + psum[2][j] + psum[3][j];
        val = h[n * HH + j] + acc / (8.0f * cntn) + bc[j];
        sv[j] = val; sv2[j] = val * val;
    }
    __syncthreads();
    ln_reduce(sv, sv2, mred, tid);
    __syncthreads();
    if (kq == 0) {
        float mean = mred[0], var = mred[1] - mean * mean;
        float hv = (val - mean) * rsqrtf(var + 1e-5f) * n1g[j] + n1b[j];
        row[j] = hv;
        h1[n * HH + j] = hv;
    }
    __syncthreads();
    gemv_pass(Wq, bq, Qo, row, psum, n, j, kq);
    gemv_pass(Wk, bk, Ko, row, psum, n, j, kq);
    gemv_pass(Wv, bv, Vo, row, psum, n, j, kq);
}

// logit table T[h][a][b] = q_a[h] . k_b[h]; also zeroes W slice. grid: 200 x 512
__launch_bounds__(512)
__global__ void k_logits(const float* __restrict__ Q, const float* __restrict__ K,
                         float* __restrict__ T, int* __restrict__ W) {
    int a = blockIdx.x, tid = threadIdx.x;
    __shared__ float Qs[HH];
    if (tid < HH) Qs[tid] = Q[a * HH + tid];
    // zero this block's W slice (800 ints)
    W[a * 800 + tid] = 0;
    if (tid < 288) W[a * 800 + 512 + tid] = 0;
    __syncthreads();
    int hh = tid >> 7, b0 = tid & 127;
    #pragma unroll
    for (int rep = 0; rep < 2; ++rep) {
        int b = b0 + rep * 128;
        if (b < NN) {
            const float* kp = K + b * HH + hh * HDIM;
            float acc = 0.0f;
            #pragma unroll
            for (int d = 0; d < HDIM; ++d) acc = fmaf(Qs[hh * HDIM + d], kp[d], acc);
            T[hh * (NN * NN) + a * NN + b] = acc;
        }
    }
}

// per-(edge,head) softmax over the 8x8 logit block; scatter weights into W (fixed-point).
// one wave per (e,h): lane = (i<<3)|j. grid: 4096 x 1024
__launch_bounds__(1024)
__global__ void k_edgesm(const int* __restrict__ hedges, const float* __restrict__ T,
                         int* __restrict__ W) {
    int tid = threadIdx.x;
    int wid = (blockIdx.x << 4) + (tid >> 6);
    int e = wid >> 2, hh = wid & 3;
    int l = tid & 63;
    int i = l >> 3, jj = l & 7;
    int a = hedges[e * SS + i];
    int b = hedges[e * SS + jj];
    float s = T[hh * (NN * NN) + a * NN + b] * 0.17677669529663687f;
    float mx = s;
    mx = fmaxf(mx, __shfl_xor(mx, 1));
    mx = fmaxf(mx, __shfl_xor(mx, 2));
    mx = fmaxf(mx, __shfl_xor(mx, 4));
    float p = __expf(s - mx);
    float sum = p;
    sum += __shfl_xor(sum, 1);
    sum += __shfl_xor(sum, 2);
    sum += __shfl_xor(sum, 4);
    float w = p / sum;
    atomicAdd(&W[hh * (NN * NN) + a * NN + b], __float2int_rn(w * WSCALE));
}

// tail: agg = (W@V)/cnt ; h2 = h1 + agg@Wo + bo ; FFN ; h = LN(h2 + FFN)
// grid: 200 x 512
__launch_bounds__(512)
__global__ void k_tail(const int* __restrict__ W, const int* __restrict__ G,
                       const float* __restrict__ h1, const float* __restrict__ V,
                       const float* __restrict__ Wo, const float* __restrict__ bo,
                       const float* __restrict__ Wf1, const float* __restrict__ bf1,
                       const float* __restrict__ Wf2, const float* __restrict__ bf2,
                       const float* __restrict__ n2g, const float* __restrict__ n2b,
                       float* __restrict__ h) {
    int n = blockIdx.x, tid = threadIdx.x;
    int j = tid & 127, kq = tid >> 7;
    __shared__ float ws8[4 * NN];
    __shared__ float aggs[HH], h2s[HH], ts[FFD];
    __shared__ float psum[4][HH];
    __shared__ float sv[HH], sv2[HH], mred[2];
    float cntn = fmaxf((float)G[n * NN + n], 1.0f);
    for (int t = tid; t < 4 * NN; t += 512) {
        int hh = t / NN, b = t - hh * NN;
        ws8[t] = (float)W[hh * (NN * NN) + n * NN + b] * WNORM;
    }
    __syncthreads();
    // agg = (W@V)/cnt
    int hj = j >> 5;
    float p = 0.0f;
    {
        int b0 = kq * 50;
        #pragma unroll 5
        for (int bb = 0; bb < 50; ++bb) p = fmaf(ws8[hj * NN + b0 + bb], V[(b0 + bb) * HH + j], p);
    }
    psum[kq][j] = p;
    __syncthreads();
    if (kq == 0) aggs[j] = (psum[0][j] + psum[1][j] + psum[2][j] + psum[3][j]) / cntn;
    __syncthreads();
    // h2 = h1 + agg@Wo + bo
    p = 0.0f;
    {
        int k0 = kq * 32;
        #pragma unroll 8
        for (int kk = 0; kk < 32; ++kk) p = fmaf(aggs[k0 + kk], Wo[(k0 + kk) * HH + j], p);
    }
    psum[kq][j] = p;
    __syncthreads();
    if (kq == 0) h2s[j] = h1[n * HH + j] + bo[j] + psum[0][j] + psum[1][j] + psum[2][j] + psum[3][j];
    __syncthreads();
    // FFN1: f = tid
    {
        float tval = bf1[tid];
        #pragma unroll 8
        for (int k = 0; k < HH; ++k) tval = fmaf(h2s[k], Wf1[k * FFD + tid], tval);
        ts[tid] = geluf(tval);
    }
    __syncthreads();
    // FFN2 split-K
    p = 0.0f;
    {
        int f0 = kq * 128;
        #pragma unroll 8
        for (int ff = 0; ff < 128; ++ff) p = fmaf(ts[f0 + ff], Wf2[(f0 + ff) * HH + j], p);
    }
    psum[kq][j] = p;
    __syncthreads();
    float o = 0.0f;
    if (kq == 0) {
        o = h2s[j] + bf2[j] + psum[0][j] + psum[1][j] + psum[2][j] + psum[3][j];
        sv[j] = o; sv2[j] = o * o;
    }
    __syncthreads();
    ln_reduce(sv, sv2, mred, tid);
    __syncthreads();
    if (kq == 0) {
        float mean = mred[0], var = mred[1] - mean * mean;
        h[n * HH + j] = (o - mean) * rsqrtf(var + 1e-5f) * n2g[j] + n2b[j];
    }
}

// Pool + heads + emb. One block, 384 threads.
__global__ void k_final(const float* __restrict__ h,
                        const float* __restrict__ Wh1, const float* __restrict__ bh1,
                        const float* __restrict__ Wh2, const float* __restrict__ bh2,
                        const float* __restrict__ Wh3, const float* __restrict__ bh3,
                        const float* __restrict__ We, const float* __restrict__ be,
                        float* __restrict__ out) {
    __shared__ float gs[384];
    __shared__ float t1s[384];
    __shared__ float t2s[192];
    int t = threadIdx.x;
    if (t < HH) {
        float sm = 0.0f, mx = -3.4e38f;
        for (int n = 0; n < NN; ++n) {
            float v = h[n * HH + t];
            sm += v;
            mx = fmaxf(mx, v);
        }
        gs[t] = sm * (1.0f / NN);
        gs[HH + t] = mx;
        gs[2 * HH + t] = sm;
    }
    __syncthreads();
    {
        int k = t >> 7, o = t & 127;
        float acc = bh1[k * 128 + o];
        for (int i = 0; i < 384; ++i) acc = fmaf(gs[i], Wh1[k * 49152 + i * 128 + o], acc);
        t1s[t] = geluf(acc);
    }
    __syncthreads();
    if (t < 192) {
        int k = t / 64, o = t % 64;
        float acc = bh2[k * 64 + o];
        for (int i = 0; i < 128; ++i) acc = fmaf(t1s[k * 128 + i], Wh2[k * 8192 + i * 64 + o], acc);
        t2s[t] = geluf(acc);
    }
    __syncthreads();
    if (t < 3) {
        float acc = bh3[t];
        for (int i = 0; i < 64; ++i) acc = fmaf(t2s[t * 64 + i], Wh3[t * 64 + i], acc);
        float r;
        if (t == 0)      r = softplusf(acc) + 1.0f;
        else if (t == 1) r = 1.0f / (1.0f + expf(-acc));
        else             r = softplusf(acc);
        out[t] = r;
    }
    if (t < HH) {
        float acc = be[t];
        for (int i = 0; i < 384; ++i) acc = fmaf(gs[i], We[i * 128 + t], acc);
        out[3 + t] = acc;
    }
}

// ---------------- launch ----------------

extern "C" void kernel_launch(void* const* d_in, const int* in_sizes, int n_in,
                              void* d_out, int out_size, void* d_ws, size_t ws_size,
                              hipStream_t stream) {
    const float* x      = (const float*)d_in[0];
    const int*   hedges = (const int*)d_in[1];
    const float* Wi     = (const float*)d_in[2];
    const float* bi     = (const float*)d_in[3];
    const float* lnig   = (const float*)d_in[4];
    const float* lnib   = (const float*)d_in[5];
    const float* Wc     = (const float*)d_in[6];
    const float* bc     = (const float*)d_in[7];
    const float* Wq     = (const float*)d_in[8];
    const float* bq     = (const float*)d_in[9];
    const float* Wk     = (const float*)d_in[10];
    const float* bk     = (const float*)d_in[11];
    const float* Wv     = (const float*)d_in[12];
    const float* bv     = (const float*)d_in[13];
    const float* Wo     = (const float*)d_in[14];
    const float* bo     = (const float*)d_in[15];
    const float* n1g    = (const float*)d_in[16];
    const float* n1b    = (const float*)d_in[17];
    const float* n2g    = (const float*)d_in[18];
    const float* n2b    = (const float*)d_in[19];
    const float* Wf1    = (const float*)d_in[20];
    const float* bf1    = (const float*)d_in[21];
    const float* Wf2    = (const float*)d_in[22];
    const float* bf2    = (const float*)d_in[23];
    const float* Wh1    = (const float*)d_in[24];
    const float* bh1    = (const float*)d_in[25];
    const float* Wh2    = (const float*)d_in[26];
    const float* bh2    = (const float*)d_in[27];
    const float* Wh3    = (const float*)d_in[28];
    const float* bh3    = (const float*)d_in[29];
    const float* We     = (const float*)d_in[30];
    const float* be     = (const float*)d_in[31];

    float* ws = (float*)d_ws;
    float* h   = ws;                     // 25600
    float* h1  = ws + 25600;             // 25600
    float* Q   = ws + 51200;             // 25600
    float* K   = ws + 76800;             // 25600
    float* V   = ws + 102400;            // 25600
    int*   G   = (int*)(ws + 128000);    // 40000
    float* T   = ws + 168000;            // 160000
    int*   W   = (int*)(ws + 328000);    // 160000

    hipMemsetAsync(G, 0, NN * NN * sizeof(int), stream);
    k_buildG<<<(EE * 64) / 256, 256, 0, stream>>>(hedges, G);
    k_embed<<<NN, HH, 0, stream>>>(x, Wi, bi, lnig, lnib, h);

    for (int l = 0; l < LL; ++l) {
        k_node1<<<NN, 512, 0, stream>>>(h, G,
            Wc + l * HH * HH, bc + l * HH,
            Wq + l * HH * HH, bq + l * HH,
            Wk + l * HH * HH, bk + l * HH,
            Wv + l * HH * HH, bv + l * HH,
            n1g + l * HH, n1b + l * HH,
            h1, Q, K, V);
        k_logits<<<NN, 512, 0, stream>>>(Q, K, T, W);
        k_edgesm<<<4096, 1024, 0, stream>>>(hedges, T, W);
        k_tail<<<NN, 512, 0, stream>>>(W, G, h1, V,
            Wo + l * HH * HH, bo + l * HH,
            Wf1 + l * HH * FFD, bf1 + l * FFD,
            Wf2 + l * FFD * HH, bf2 + l * HH,
            n2g + l * HH, n2b + l * HH, h);
    }

    k_final<<<1, 384, 0, stream>>>(h, Wh1, bh1, Wh2, bh2, Wh3, bh3, We, be, (float*)d_out);
}

// Round 3
// 396.160 us; speedup vs baseline: 4.1693x; 2.7985x over previous
//
#include <hip/hip_runtime.h>
#include <hip/hip_bf16.h>
#include <math.h>

#define NN 200
#define DD 8
#define HH 128
#define NHEAD 4
#define HDIM 32
#define LL 6
#define EE 16384
#define SS 8
#define FFD 512

#define WSCALE 1048576.0f       // 2^20 fixed-point scale for attention-weight atomics
#define WNORM  (1.0f/1048576.0f)
#define RSCALE 0.17677669529663687f   // 1/sqrt(32)

// ---------------- helpers ----------------

__device__ __forceinline__ float geluf(float x) {
    return 0.5f * x * (1.0f + erff(x * 0.70710678118654752f));
}
__device__ __forceinline__ float softplusf(float x) {
    return (x > 20.0f) ? x : log1pf(expf(x));
}

// LN mean/var reduce over sv/sv2[128] using first wave; results in mred[0..1]
__device__ __forceinline__ void ln_reduce(const float* sv, const float* sv2, float* mred, int tid) {
    if (tid < 64) {
        float s1 = sv[tid] + sv[tid + 64];
        float s2 = sv2[tid] + sv2[tid + 64];
        #pragma unroll
        for (int m = 32; m > 0; m >>= 1) {
            s1 += __shfl_xor(s1, m);
            s2 += __shfl_xor(s2, m);
        }
        if (tid == 0) { mred[0] = s1 * (1.0f / HH); mred[1] = s2 * (1.0f / HH); }
    }
}

// ---------------- one-time setup kernels ----------------

// G[a][b] = #edges containing both a and b
__global__ void k_buildG(const int* __restrict__ hedges, int* __restrict__ G) {
    int gid = blockIdx.x * 256 + threadIdx.x;
    if (gid >= EE * 64) return;
    int e = gid >> 6, p = gid & 63;
    int a = hedges[e * SS + (p >> 3)];
    int b = hedges[e * SS + (p & 7)];
    atomicAdd(&G[a * NN + b], 1);
}

// CSR offsets from G diagonal (exclusive scan over 200 counts); zero fill[]
__global__ void k_csrOff(const int* __restrict__ G, int* __restrict__ off, int* __restrict__ fill) {
    __shared__ int s[256];
    int t = threadIdx.x;
    int c = (t < NN) ? G[t * NN + t] : 0;
    s[t] = c;
    __syncthreads();
    for (int d = 1; d < 256; d <<= 1) {
        int v = (t >= d) ? s[t - d] : 0;
        __syncthreads();
        s[t] += v;
        __syncthreads();
    }
    off[t] = s[t] - c;   // exclusive prefix
    fill[t] = 0;
}

// csr[off[a] + slot] = edge id, for each membership (order-independent downstream)
__global__ void k_fillCSR(const int* __restrict__ hedges, const int* __restrict__ off,
                          int* __restrict__ fill, int* __restrict__ csr) {
    int t = blockIdx.x * 256 + threadIdx.x;
    if (t >= EE * SS) return;
    int a = hedges[t];
    int slot = atomicAdd(&fill[a], 1);
    csr[off[a] + slot] = t >> 3;   // edge id
}

// ---------------- model kernels ----------------

// h0 = gelu(LN(x@Wi+bi)) + PE     grid: 200 x 128
__global__ void k_embed(const float* __restrict__ x, const float* __restrict__ Wi,
                        const float* __restrict__ bi, const float* __restrict__ lnig,
                        const float* __restrict__ lnib, float* __restrict__ h) {
    int n = blockIdx.x, j = threadIdx.x;
    __shared__ float sv[HH], sv2[HH], mred[2];
    float s = bi[j];
    #pragma unroll
    for (int d = 0; d < DD; ++d) s = fmaf(x[n * DD + d], Wi[d * HH + j], s);
    sv[j] = s; sv2[j] = s * s;
    __syncthreads();
    ln_reduce(sv, sv2, mred, j);
    __syncthreads();
    float mean = mred[0], var = mred[1] - mean * mean;
    float v = (s - mean) * rsqrtf(var + 1e-5f) * lnig[j] + lnib[j];
    float ge = geluf(v);
    int i2 = (j >> 1) * 2;
    float div = expf((float)i2 * (-9.210340371976184f / 128.0f));
    float ang = (float)n * div;
    float pe = (j & 1) ? cosf(ang) : sinf(ang);
    h[n * HH + j] = ge + pe;
}

// node phase 1: hg = G@h ; h1 = LN(h + (hg@Wc)/(8*cnt) + bc) ; Q,K,V = h1@W+b
// grid: 200 x 512
__launch_bounds__(512)
__global__ void k_node1(const float* __restrict__ h, const int* __restrict__ G,
                        const float* __restrict__ Wc, const float* __restrict__ bc,
                        const float* __restrict__ Wq, const float* __restrict__ bq,
                        const float* __restrict__ Wk, const float* __restrict__ bk,
                        const float* __restrict__ Wv, const float* __restrict__ bv,
                        const float* __restrict__ n1g, const float* __restrict__ n1b,
                        float* __restrict__ h1, float* __restrict__ Qo,
                        float* __restrict__ Ko, float* __restrict__ Vo) {
    int n = blockIdx.x, tid = threadIdx.x;
    int j = tid & 127, kq = tid >> 7;
    __shared__ float Gs[NN];
    __shared__ float row[HH];
    __shared__ float psA[4][HH];
    __shared__ float psB[4][HH];
    __shared__ float psC[4][HH];
    __shared__ float sv[HH], sv2[HH], mred[2];
    for (int m = tid; m < NN; m += 512) Gs[m] = (float)G[n * NN + m];
    __syncthreads();
    float cntn = fmaxf(Gs[n], 1.0f);
    // hg = G@h (split over 4 chunks of 50 rows)
    float p = 0.0f;
    {
        int m0 = kq * 50;
        #pragma unroll 5
        for (int mm = 0; mm < 50; ++mm) p = fmaf(Gs[m0 + mm], h[(m0 + mm) * HH + j], p);
    }
    psA[kq][j] = p;
    __syncthreads();
    if (kq == 0) row[j] = psA[0][j] + psA[1][j] + psA[2][j] + psA[3][j];
    __syncthreads();
    // conv GEMV
    p = 0.0f;
    {
        int k0 = kq * 32;
        #pragma unroll 8
        for (int kk = 0; kk < 32; ++kk) p = fmaf(row[k0 + kk], Wc[(k0 + kk) * HH + j], p);
    }
    psA[kq][j] = p;
    __syncthreads();
    float val = 0.0f;
    if (kq == 0) {
        float acc = psA[0][j] + psA[1][j] + psA[2][j] + psA[3][j];
        val = h[n * HH + j] + acc / (8.0f * cntn) + bc[j];
        sv[j] = val; sv2[j] = val * val;
    }
    __syncthreads();
    ln_reduce(sv, sv2, mred, tid);
    __syncthreads();
    if (kq == 0) {
        float mean = mred[0], var = mred[1] - mean * mean;
        float hv = (val - mean) * rsqrtf(var + 1e-5f) * n1g[j] + n1b[j];
        row[j] = hv;
        h1[n * HH + j] = hv;
    }
    __syncthreads();
    // merged Q,K,V GEMVs (3 accumulators, one pass)
    float pq = 0.0f, pk = 0.0f, pv = 0.0f;
    {
        int k0 = kq * 32;
        #pragma unroll 4
        for (int kk = 0; kk < 32; ++kk) {
            float r = row[k0 + kk];
            int idx = (k0 + kk) * HH + j;
            pq = fmaf(r, Wq[idx], pq);
            pk = fmaf(r, Wk[idx], pk);
            pv = fmaf(r, Wv[idx], pv);
        }
    }
    psA[kq][j] = pq; psB[kq][j] = pk; psC[kq][j] = pv;
    __syncthreads();
    if (kq == 0) {
        Qo[n * HH + j] = bq[j] + psA[0][j] + psA[1][j] + psA[2][j] + psA[3][j];
        Ko[n * HH + j] = bk[j] + psB[0][j] + psB[1][j] + psB[2][j] + psB[3][j];
        Vo[n * HH + j] = bv[j] + psC[0][j] + psC[1][j] + psC[2][j] + psC[3][j];
    }
}

// Edge attention + aggregation, one block per node. grid: 200 x 512
// LDS-staged K -> logit row Ts; LDS-staged V; per-membership softmax scattered
// into LDS int fixed-point Wrow; dense Wrow@V; fused Wo GEMV -> h2.
__launch_bounds__(512)
__global__ void k_edgeagg(const float* __restrict__ Q, const float* __restrict__ K,
                          const float* __restrict__ V, const int* __restrict__ hedges,
                          const int* __restrict__ csr, const int* __restrict__ off,
                          const int* __restrict__ G, const float* __restrict__ h1,
                          const float* __restrict__ Wo, const float* __restrict__ bo,
                          float* __restrict__ h2) {
    __shared__ float Vs[NN * HH];     // 100 KB (used as K first, then V)
    __shared__ float Ts[NHEAD * NN];  // logit row
    __shared__ int   Wrow[NHEAD * NN];
    __shared__ float Qs[HH];
    __shared__ float psum[4][HH];
    __shared__ float aggs[HH];

    int a = blockIdx.x, tid = threadIdx.x;
    int cnt = G[a * NN + a];
    int off_a = off[a];
    float cntn = fmaxf((float)cnt, 1.0f);

    // stage K into Vs, load Q row, zero Wrow
    {
        const float4* Ksrc = (const float4*)K;
        float4* Vdst = (float4*)Vs;
        for (int idx = tid; idx < NN * HH / 4; idx += 512) Vdst[idx] = Ksrc[idx];
    }
    if (tid < HH) Qs[tid] = Q[a * HH + tid];
    for (int t = tid; t < NHEAD * NN; t += 512) Wrow[t] = 0;
    __syncthreads();

    // Ts[h][b] = (q_a[h] . k_b[h]) * RSCALE   (rotation-indexed: conflict-free)
    for (int task = tid; task < 1024; task += 512) {
        int hh = task >> 8, b = task & 255;
        if (b < NN) {
            int base = b * HH + hh * HDIM;
            float acc = 0.0f;
            #pragma unroll
            for (int t = 0; t < HDIM; ++t) {
                int d = (t + b) & 31;
                acc = fmaf(Qs[hh * HDIM + d], Vs[base + d], acc);
            }
            Ts[hh * NN + b] = acc * RSCALE;
        }
    }
    __syncthreads();

    // stage V (overwrite K)
    {
        const float4* Vsrc = (const float4*)V;
        float4* Vdst = (float4*)Vs;
        for (int idx = tid; idx < NN * HH / 4; idx += 512) Vdst[idx] = Vsrc[idx];
    }
    __syncthreads();

    // phase A: per (membership, head): softmax over 8 logits, scatter to Wrow
    int ntask = cnt * NHEAD;
    for (int t = tid; t < ntask; t += 512) {
        int m = t >> 2, hh = t & 3;
        int e = csr[off_a + m];
        int4 e0 = ((const int4*)hedges)[e * 2];
        int4 e1 = ((const int4*)hedges)[e * 2 + 1];
        int b0 = e0.x, b1 = e0.y, b2 = e0.z, b3 = e0.w;
        int b4 = e1.x, b5 = e1.y, b6 = e1.z, b7 = e1.w;
        const float* Tr = Ts + hh * NN;
        float l0 = Tr[b0], l1 = Tr[b1], l2 = Tr[b2], l3 = Tr[b3];
        float l4 = Tr[b4], l5 = Tr[b5], l6 = Tr[b6], l7 = Tr[b7];
        float mx = fmaxf(fmaxf(fmaxf(l0, l1), fmaxf(l2, l3)),
                         fmaxf(fmaxf(l4, l5), fmaxf(l6, l7)));
        l0 = __expf(l0 - mx); l1 = __expf(l1 - mx); l2 = __expf(l2 - mx); l3 = __expf(l3 - mx);
        l4 = __expf(l4 - mx); l5 = __expf(l5 - mx); l6 = __expf(l6 - mx); l7 = __expf(l7 - mx);
        float inv = WSCALE / (l0 + l1 + l2 + l3 + l4 + l5 + l6 + l7);
        int* Wr = Wrow + hh * NN;
        atomicAdd(&Wr[b0], __float2int_rn(l0 * inv));
        atomicAdd(&Wr[b1], __float2int_rn(l1 * inv));
        atomicAdd(&Wr[b2], __float2int_rn(l2 * inv));
        atomicAdd(&Wr[b3], __float2int_rn(l3 * inv));
        atomicAdd(&Wr[b4], __float2int_rn(l4 * inv));
        atomicAdd(&Wr[b5], __float2int_rn(l5 * inv));
        atomicAdd(&Wr[b6], __float2int_rn(l6 * inv));
        atomicAdd(&Wr[b7], __float2int_rn(l7 * inv));
    }
    __syncthreads();

    // phase B: agg[h*32+d] = sum_b Wrow[h][b] * Vs[b][h*32+d]  (4-way split over b)
    {
        int sc = tid >> 7, hh = (tid >> 5) & 3, d = tid & 31;
        float acc = 0.0f;
        int bb0 = sc * 50;
        #pragma unroll 5
        for (int bb = 0; bb < 50; ++bb) {
            int b = bb0 + bb;
            acc = fmaf((float)Wrow[hh * NN + b], Vs[b * HH + hh * HDIM + d], acc);
        }
        psum[sc][hh * HDIM + d] = acc;
    }
    __syncthreads();
    if (tid < HH) aggs[tid] = (psum[0][tid] + psum[1][tid] + psum[2][tid] + psum[3][tid]) * WNORM / cntn;
    __syncthreads();
    // fused: h2 = h1 + agg@Wo + bo
    {
        int kq = tid >> 7, j = tid & 127;
        float p = 0.0f;
        int k0 = kq * 32;
        #pragma unroll 8
        for (int kk = 0; kk < 32; ++kk) p = fmaf(aggs[k0 + kk], Wo[(k0 + kk) * HH + j], p);
        psum[kq][j] = p;
    }
    __syncthreads();
    if (tid < HH)
        h2[a * HH + tid] = h1[a * HH + tid] + bo[tid] + psum[0][tid] + psum[1][tid] + psum[2][tid] + psum[3][tid];
}

// tail: FFN over h2 ; h = LN(h2 + FFN)    grid: 200 x 512
__launch_bounds__(512)
__global__ void k_tail(const float* __restrict__ h2,
                       const float* __restrict__ Wf1, const float* __restrict__ bf1,
                       const float* __restrict__ Wf2, const float* __restrict__ bf2,
                       const float* __restrict__ n2g, const float* __restrict__ n2b,
                       float* __restrict__ h) {
    int n = blockIdx.x, tid = threadIdx.x;
    int j = tid & 127, kq = tid >> 7;
    __shared__ float h2s[HH], ts[FFD];
    __shared__ float psum[4][HH];
    __shared__ float sv[HH], sv2[HH], mred[2];
    if (tid < HH) h2s[tid] = h2[n * HH + tid];
    __syncthreads();
    // FFN1: f = tid
    {
        float tval = bf1[tid];
        #pragma unroll 8
        for (int k = 0; k < HH; ++k) tval = fmaf(h2s[k], Wf1[k * FFD + tid], tval);
        ts[tid] = geluf(tval);
    }
    __syncthreads();
    // FFN2 split-K
    float p = 0.0f;
    {
        int f0 = kq * 128;
        #pragma unroll 8
        for (int ff = 0; ff < 128; ++ff) p = fmaf(ts[f0 + ff], Wf2[(f0 + ff) * HH + j], p);
    }
    psum[kq][j] = p;
    __syncthreads();
    float o = 0.0f;
    if (kq == 0) {
        o = h2s[j] + bf2[j] + psum[0][j] + psum[1][j] + psum[2][j] + psum[3][j];
        sv[j] = o; sv2[j] = o * o;
    }
    __syncthreads();
    ln_reduce(sv, sv2, mred, tid);
    __syncthreads();
    if (kq == 0) {
        float mean = mred[0], var = mred[1] - mean * mean;
        h[n * HH + j] = (o - mean) * rsqrtf(var + 1e-5f) * n2g[j] + n2b[j];
    }
}

// Pool + heads + emb. One block, 384 threads.
__global__ void k_final(const float* __restrict__ h,
                        const float* __restrict__ Wh1, const float* __restrict__ bh1,
                        const float* __restrict__ Wh2, const float* __restrict__ bh2,
                        const float* __restrict__ Wh3, const float* __restrict__ bh3,
                        const float* __restrict__ We, const float* __restrict__ be,
                        float* __restrict__ out) {
    __shared__ float gs[384];
    __shared__ float t1s[384];
    __shared__ float t2s[192];
    int t = threadIdx.x;
    if (t < HH) {
        float sm = 0.0f, mx = -3.4e38f;
        for (int n = 0; n < NN; ++n) {
            float v = h[n * HH + t];
            sm += v;
            mx = fmaxf(mx, v);
        }
        gs[t] = sm * (1.0f / NN);
        gs[HH + t] = mx;
        gs[2 * HH + t] = sm;
    }
    __syncthreads();
    {
        int k = t >> 7, o = t & 127;
        float acc = bh1[k * 128 + o];
        for (int i = 0; i < 384; ++i) acc = fmaf(gs[i], Wh1[k * 49152 + i * 128 + o], acc);
        t1s[t] = geluf(acc);
    }
    __syncthreads();
    if (t < 192) {
        int k = t / 64, o = t % 64;
        float acc = bh2[k * 64 + o];
        for (int i = 0; i < 128; ++i) acc = fmaf(t1s[k * 128 + i], Wh2[k * 8192 + i * 64 + o], acc);
        t2s[t] = geluf(acc);
    }
    __syncthreads();
    if (t < 3) {
        float acc = bh3[t];
        for (int i = 0; i < 64; ++i) acc = fmaf(t2s[t * 64 + i], Wh3[t * 64 + i], acc);
        float r;
        if (t == 0)      r = softplusf(acc) + 1.0f;
        else if (t == 1) r = 1.0f / (1.0f + expf(-acc));
        else             r = softplusf(acc);
        out[t] = r;
    }
    if (t < HH) {
        float acc = be[t];
        for (int i = 0; i < 384; ++i) acc = fmaf(gs[i], We[i * 128 + t], acc);
        out[3 + t] = acc;
    }
}

// ---------------- launch ----------------

extern "C" void kernel_launch(void* const* d_in, const int* in_sizes, int n_in,
                              void* d_out, int out_size, void* d_ws, size_t ws_size,
                              hipStream_t stream) {
    const float* x      = (const float*)d_in[0];
    const int*   hedges = (const int*)d_in[1];
    const float* Wi     = (const float*)d_in[2];
    const float* bi     = (const float*)d_in[3];
    const float* lnig   = (const float*)d_in[4];
    const float* lnib   = (const float*)d_in[5];
    const float* Wc     = (const float*)d_in[6];
    const float* bc     = (const float*)d_in[7];
    const float* Wq     = (const float*)d_in[8];
    const float* bq     = (const float*)d_in[9];
    const float* Wk     = (const float*)d_in[10];
    const float* bk     = (const float*)d_in[11];
    const float* Wv     = (const float*)d_in[12];
    const float* bv     = (const float*)d_in[13];
    const float* Wo     = (const float*)d_in[14];
    const float* bo     = (const float*)d_in[15];
    const float* n1g    = (const float*)d_in[16];
    const float* n1b    = (const float*)d_in[17];
    const float* n2g    = (const float*)d_in[18];
    const float* n2b    = (const float*)d_in[19];
    const float* Wf1    = (const float*)d_in[20];
    const float* bf1    = (const float*)d_in[21];
    const float* Wf2    = (const float*)d_in[22];
    const float* bf2    = (const float*)d_in[23];
    const float* Wh1    = (const float*)d_in[24];
    const float* bh1    = (const float*)d_in[25];
    const float* Wh2    = (const float*)d_in[26];
    const float* bh2    = (const float*)d_in[27];
    const float* Wh3    = (const float*)d_in[28];
    const float* bh3    = (const float*)d_in[29];
    const float* We     = (const float*)d_in[30];
    const float* be     = (const float*)d_in[31];

    float* ws = (float*)d_ws;
    float* h    = ws;                     // 25600
    float* h1   = ws + 25600;             // 25600
    float* h2   = ws + 51200;             // 25600
    float* Q    = ws + 76800;             // 25600
    float* K    = ws + 102400;            // 25600
    float* V    = ws + 128000;            // 25600
    int*   G    = (int*)(ws + 153600);    // 40000 ints
    int*   off  = (int*)(ws + 193600);    // 256 ints
    int*   fill = (int*)(ws + 193856);    // 256 ints
    int*   csr  = (int*)(ws + 194112);    // 131072 ints

    hipMemsetAsync(G, 0, NN * NN * sizeof(int), stream);
    k_buildG<<<(EE * 64) / 256, 256, 0, stream>>>(hedges, G);
    k_csrOff<<<1, 256, 0, stream>>>(G, off, fill);
    k_fillCSR<<<(EE * SS) / 256, 256, 0, stream>>>(hedges, off, fill, csr);
    k_embed<<<NN, HH, 0, stream>>>(x, Wi, bi, lnig, lnib, h);

    for (int l = 0; l < LL; ++l) {
        k_node1<<<NN, 512, 0, stream>>>(h, G,
            Wc + l * HH * HH, bc + l * HH,
            Wq + l * HH * HH, bq + l * HH,
            Wk + l * HH * HH, bk + l * HH,
            Wv + l * HH * HH, bv + l * HH,
            n1g + l * HH, n1b + l * HH,
            h1, Q, K, V);
        k_edgeagg<<<NN, 512, 0, stream>>>(Q, K, V, hedges, csr, off, G, h1,
            Wo + l * HH * HH, bo + l * HH, h2);
        k_tail<<<NN, 512, 0, stream>>>(h2,
            Wf1 + l * HH * FFD, bf1 + l * FFD,
            Wf2 + l * FFD * HH, bf2 + l * HH,
            n2g + l * HH, n2b + l * HH, h);
    }

    k_final<<<1, 384, 0, stream>>>(h, Wh1, bh1, Wh2, bh2, Wh3, bh3, We, be, (float*)d_out);
}

// Round 4
// 261.239 us; speedup vs baseline: 6.3227x; 1.5165x over previous
//
#include <hip/hip_runtime.h>
#include <hip/hip_bf16.h>
#include <math.h>

#define NN 200
#define DD 8
#define HH 128
#define NHEAD 4
#define HDIM 32
#define LL 6
#define EE 16384
#define SS 8
#define FFD 512
#define W64 256                  // EE/64 bitmap words per node column

#define WSCALE 1048576.0f        // 2^20 fixed-point scale for LDS int attention atomics
#define WNORM  (1.0f/1048576.0f)
#define RSCALE 0.17677669529663687f   // 1/sqrt(32)

// ---------------- helpers ----------------

__device__ __forceinline__ float geluf(float x) {
    return 0.5f * x * (1.0f + erff(x * 0.70710678118654752f));
}
__device__ __forceinline__ float softplusf(float x) {
    return (x > 20.0f) ? x : log1pf(expf(x));
}

// LN mean/var reduce over sv/sv2[128] using first wave; results in mred[0..1]
__device__ __forceinline__ void ln_reduce(const float* sv, const float* sv2, float* mred, int tid) {
    if (tid < 64) {
        float s1 = sv[tid] + sv[tid + 64];
        float s2 = sv2[tid] + sv2[tid + 64];
        #pragma unroll
        for (int m = 32; m > 0; m >>= 1) {
            s1 += __shfl_xor(s1, m);
            s2 += __shfl_xor(s2, m);
        }
        if (tid == 0) { mred[0] = s1 * (1.0f / HH); mred[1] = s2 * (1.0f / HH); }
    }
}

// ---------------- setup: bitmap + popcount co-occurrence ----------------

// bmT[w][n] bit b set iff node n is a member of edge w*64+b
__global__ void k_bitmap(const int* __restrict__ hedges, unsigned long long* __restrict__ bmT) {
    int t = blockIdx.x * 256 + threadIdx.x;
    if (t >= EE * SS) return;
    int n = hedges[t];
    int e = t >> 3;
    atomicOr(&bmT[(e >> 6) * NN + n], 1ULL << (e & 63));
}

// G[a][b] = popcount(col_a & col_b)  — deterministic, no atomics
__global__ void k_buildG2(const unsigned long long* __restrict__ bmT, int* __restrict__ G) {
    __shared__ unsigned long long colA[W64];
    int a = blockIdx.x, tid = threadIdx.x;
    for (int w = tid; w < W64; w += 256) colA[w] = bmT[w * NN + a];
    __syncthreads();
    if (tid < NN) {
        int acc = 0;
        #pragma unroll 8
        for (int w = 0; w < W64; ++w) acc += __popcll(colA[w] & bmT[w * NN + tid]);
        G[a * NN + tid] = acc;
    }
}

// ---------------- model kernels ----------------

// h0 = gelu(LN(x@Wi+bi)) + PE ; hc0 = h0 @ Wc[0]     grid: 200 x 512
__launch_bounds__(512)
__global__ void k_embed(const float* __restrict__ x, const float* __restrict__ Wi,
                        const float* __restrict__ bi, const float* __restrict__ lnig,
                        const float* __restrict__ lnib, const float* __restrict__ Wc0,
                        float* __restrict__ h, float* __restrict__ hc) {
    int n = blockIdx.x, tid = threadIdx.x;
    int j = tid & 127, kq = tid >> 7;
    __shared__ float sv[HH], sv2[HH], mred[2], row[HH], psum[4][HH];
    float s = 0.0f;
    if (kq == 0) {
        s = bi[j];
        #pragma unroll
        for (int d = 0; d < DD; ++d) s = fmaf(x[n * DD + d], Wi[d * HH + j], s);
        sv[j] = s; sv2[j] = s * s;
    }
    __syncthreads();
    ln_reduce(sv, sv2, mred, tid);
    __syncthreads();
    if (kq == 0) {
        float mean = mred[0], var = mred[1] - mean * mean;
        float v = (s - mean) * rsqrtf(var + 1e-5f) * lnig[j] + lnib[j];
        float ge = geluf(v);
        int i2 = (j >> 1) * 2;
        float div = expf((float)i2 * (-9.210340371976184f / 128.0f));
        float ang = (float)n * div;
        float pe = (j & 1) ? cosf(ang) : sinf(ang);
        float hv = ge + pe;
        row[j] = hv;
        h[n * HH + j] = hv;
    }
    __syncthreads();
    float p = 0.0f;
    {
        int k0 = kq * 32;
        #pragma unroll 8
        for (int kk = 0; kk < 32; ++kk) p = fmaf(row[k0 + kk], Wc0[(k0 + kk) * HH + j], p);
    }
    psum[kq][j] = p;
    __syncthreads();
    if (kq == 0) hc[n * HH + j] = psum[0][j] + psum[1][j] + psum[2][j] + psum[3][j];
}

// node phase: acc = G@hc ; h1 = LN(h + acc/(8*cnt) + bc) ; Q,K,V = h1@W+b
// grid: 200 x 512
__launch_bounds__(512)
__global__ void k_node1(const float* __restrict__ h, const float* __restrict__ hc,
                        const int* __restrict__ G, const float* __restrict__ bc,
                        const float* __restrict__ Wq, const float* __restrict__ bq,
                        const float* __restrict__ Wk, const float* __restrict__ bk,
                        const float* __restrict__ Wv, const float* __restrict__ bv,
                        const float* __restrict__ n1g, const float* __restrict__ n1b,
                        float* __restrict__ h1, float* __restrict__ Qo,
                        float* __restrict__ Ko, float* __restrict__ Vo) {
    int n = blockIdx.x, tid = threadIdx.x;
    int j = tid & 127, kq = tid >> 7;
    __shared__ float Gs[NN];
    __shared__ float row[HH];
    __shared__ float psA[4][HH], psB[4][HH], psC[4][HH];
    __shared__ float sv[HH], sv2[HH], mred[2];
    for (int m = tid; m < NN; m += 512) Gs[m] = (float)G[n * NN + m];
    __syncthreads();
    float cntn = fmaxf(Gs[n], 1.0f);
    float p = 0.0f;
    {
        int m0 = kq * 50;
        #pragma unroll 5
        for (int mm = 0; mm < 50; ++mm) p = fmaf(Gs[m0 + mm], hc[(m0 + mm) * HH + j], p);
    }
    psA[kq][j] = p;
    __syncthreads();
    float val = 0.0f;
    if (kq == 0) {
        float acc = psA[0][j] + psA[1][j] + psA[2][j] + psA[3][j];
        val = h[n * HH + j] + acc / (8.0f * cntn) + bc[j];
        sv[j] = val; sv2[j] = val * val;
    }
    __syncthreads();
    ln_reduce(sv, sv2, mred, tid);
    __syncthreads();
    if (kq == 0) {
        float mean = mred[0], var = mred[1] - mean * mean;
        float hv = (val - mean) * rsqrtf(var + 1e-5f) * n1g[j] + n1b[j];
        row[j] = hv;
        h1[n * HH + j] = hv;
    }
    __syncthreads();
    float pq = 0.0f, pk = 0.0f, pv = 0.0f;
    {
        int k0 = kq * 32;
        #pragma unroll 4
        for (int kk = 0; kk < 32; ++kk) {
            float r = row[k0 + kk];
            int idx = (k0 + kk) * HH + j;
            pq = fmaf(r, Wq[idx], pq);
            pk = fmaf(r, Wk[idx], pk);
            pv = fmaf(r, Wv[idx], pv);
        }
    }
    psA[kq][j] = pq; psB[kq][j] = pk; psC[kq][j] = pv;
    __syncthreads();
    if (kq == 0) {
        Qo[n * HH + j] = bq[j] + psA[0][j] + psA[1][j] + psA[2][j] + psA[3][j];
        Ko[n * HH + j] = bk[j] + psB[0][j] + psB[1][j] + psB[2][j] + psB[3][j];
        Vo[n * HH + j] = bv[j] + psC[0][j] + psC[1][j] + psC[2][j] + psC[3][j];
    }
}

// Fused edge attention + aggregation + Wo + FFN + LN (+ next-layer hc).
// One block per node a. grid: 200 x 512
__launch_bounds__(512)
__global__ void k_edgefused(const float* __restrict__ Q, const float* __restrict__ K,
                            const float* __restrict__ V, const int* __restrict__ hedges,
                            const unsigned long long* __restrict__ bmT,
                            const float* __restrict__ h1,
                            const float* __restrict__ Wo, const float* __restrict__ bo,
                            const float* __restrict__ Wf1, const float* __restrict__ bf1,
                            const float* __restrict__ Wf2, const float* __restrict__ bf2,
                            const float* __restrict__ n2g, const float* __restrict__ n2b,
                            const float* __restrict__ WcN,
                            float* __restrict__ h, float* __restrict__ hc) {
    __shared__ float Vs[NN * HH];        // 100 KB V stage
    __shared__ float Ts[NHEAD * NN];     // logit row
    __shared__ int   Wrow[NHEAD * NN];   // fixed-point weight row
    __shared__ int   list[1024];         // member edge ids
    __shared__ float Qs[HH];
    __shared__ float psum[4][HH];
    __shared__ float sv[HH], sv2[HH], mred[2];
    __shared__ float aggs[HH], h2s[HH], rowN[HH];
    __shared__ float ts[FFD];
    __shared__ int wsum[8];
    __shared__ int wtot;

    int a = blockIdx.x, tid = threadIdx.x;
    int j = tid & 127, kq = tid >> 7;

    // stage V, load Q row, zero Wrow
    {
        const float4* src = (const float4*)V;
        float4* dst = (float4*)Vs;
        for (int i = tid; i < NN * HH / 4; i += 512) dst[i] = src[i];
    }
    if (tid < HH) Qs[tid] = Q[a * HH + tid];
    for (int t = tid; t < NHEAD * NN; t += 512) Wrow[t] = 0;

    // extract member-edge list from bitmap column a (deterministic prefix-scan)
    unsigned long long w = (tid < W64) ? bmT[tid * NN + a] : 0ULL;
    int c = __popcll(w);
    int lane = tid & 63, wid = tid >> 6;
    int incl = c;
    #pragma unroll
    for (int m = 1; m < 64; m <<= 1) {
        int v = __shfl_up(incl, m);
        if (lane >= m) incl += v;
    }
    if (lane == 63) wsum[wid] = incl;
    __syncthreads();
    if (tid == 0) {
        int s = 0;
        #pragma unroll
        for (int i = 0; i < 8; ++i) { int v = wsum[i]; wsum[i] = s; s += v; }
        wtot = s;
    }
    __syncthreads();
    {
        int base = wsum[wid] + incl - c;
        unsigned long long ww = w;
        while (ww) {
            int b = __ffsll((long long)ww) - 1;
            ww &= ww - 1;
            list[base++] = tid * 64 + b;
        }
    }
    int cnt = wtot;
    float cntn = fmaxf((float)cnt, 1.0f);

    // Ts[h][b] = (q_a[h] . k_b[h]) * RSCALE   (K direct from global/L2)
    for (int task = tid; task < 1024; task += 512) {
        int hh = task >> 8, b = task & 255;
        if (b < NN) {
            const float4* kp4 = (const float4*)(K + b * HH + hh * HDIM);
            const float4* qp4 = (const float4*)(Qs + hh * HDIM);
            float acc = 0.0f;
            #pragma unroll
            for (int u = 0; u < 8; ++u) {
                float4 kv = kp4[u], qv = qp4[u];
                acc += qv.x * kv.x + qv.y * kv.y + qv.z * kv.z + qv.w * kv.w;
            }
            Ts[hh * NN + b] = acc * RSCALE;
        }
    }
    __syncthreads();   // Vs, Wrow, list, Ts all ready

    // phase A: per (member-edge, head): softmax over 8 logits -> scatter to Wrow
    int ntask = cnt * NHEAD;
    for (int t = tid; t < ntask; t += 512) {
        int m = t >> 2, hh = t & 3;
        int e = list[m];
        int4 e0 = ((const int4*)hedges)[e * 2];
        int4 e1 = ((const int4*)hedges)[e * 2 + 1];
        const float* Tr = Ts + hh * NN;
        float l0 = Tr[e0.x], l1 = Tr[e0.y], l2 = Tr[e0.z], l3 = Tr[e0.w];
        float l4 = Tr[e1.x], l5 = Tr[e1.y], l6 = Tr[e1.z], l7 = Tr[e1.w];
        float mx = fmaxf(fmaxf(fmaxf(l0, l1), fmaxf(l2, l3)),
                         fmaxf(fmaxf(l4, l5), fmaxf(l6, l7)));
        l0 = __expf(l0 - mx); l1 = __expf(l1 - mx); l2 = __expf(l2 - mx); l3 = __expf(l3 - mx);
        l4 = __expf(l4 - mx); l5 = __expf(l5 - mx); l6 = __expf(l6 - mx); l7 = __expf(l7 - mx);
        float inv = WSCALE / (l0 + l1 + l2 + l3 + l4 + l5 + l6 + l7);
        int* Wr = Wrow + hh * NN;
        atomicAdd(&Wr[e0.x], __float2int_rn(l0 * inv));
        atomicAdd(&Wr[e0.y], __float2int_rn(l1 * inv));
        atomicAdd(&Wr[e0.z], __float2int_rn(l2 * inv));
        atomicAdd(&Wr[e0.w], __float2int_rn(l3 * inv));
        atomicAdd(&Wr[e1.x], __float2int_rn(l4 * inv));
        atomicAdd(&Wr[e1.y], __float2int_rn(l5 * inv));
        atomicAdd(&Wr[e1.z], __float2int_rn(l6 * inv));
        atomicAdd(&Wr[e1.w], __float2int_rn(l7 * inv));
    }
    __syncthreads();

    // phase B: agg[h*32+d] = sum_b Wrow[h][b] * Vs[b][h*32+d]
    {
        int sc = tid >> 7, hh = (tid >> 5) & 3, d = tid & 31;
        float acc = 0.0f;
        int b0 = sc * 50;
        #pragma unroll 5
        for (int bb = 0; bb < 50; ++bb) {
            int b = b0 + bb;
            acc = fmaf((float)Wrow[hh * NN + b], Vs[b * HH + hh * HDIM + d], acc);
        }
        psum[sc][hh * HDIM + d] = acc;
    }
    __syncthreads();
    if (tid < HH) aggs[tid] = (psum[0][tid] + psum[1][tid] + psum[2][tid] + psum[3][tid]) * WNORM / cntn;
    __syncthreads();
    // h2 = h1 + agg@Wo + bo
    {
        float p = 0.0f;
        int k0 = kq * 32;
        #pragma unroll 8
        for (int kk = 0; kk < 32; ++kk) p = fmaf(aggs[k0 + kk], Wo[(k0 + kk) * HH + j], p);
        psum[kq][j] = p;
    }
    __syncthreads();
    if (tid < HH) h2s[tid] = h1[a * HH + tid] + bo[tid] + psum[0][tid] + psum[1][tid] + psum[2][tid] + psum[3][tid];
    __syncthreads();
    // FFN1
    {
        float tval = bf1[tid];
        #pragma unroll 8
        for (int k = 0; k < HH; ++k) tval = fmaf(h2s[k], Wf1[k * FFD + tid], tval);
        ts[tid] = geluf(tval);
    }
    __syncthreads();
    // FFN2 split-K
    {
        float p = 0.0f;
        int f0 = kq * 128;
        #pragma unroll 8
        for (int ff = 0; ff < 128; ++ff) p = fmaf(ts[f0 + ff], Wf2[(f0 + ff) * HH + j], p);
        psum[kq][j] = p;
    }
    __syncthreads();
    float o = 0.0f;
    if (kq == 0) {
        o = h2s[j] + bf2[j] + psum[0][j] + psum[1][j] + psum[2][j] + psum[3][j];
        sv[j] = o; sv2[j] = o * o;
    }
    __syncthreads();
    ln_reduce(sv, sv2, mred, tid);
    __syncthreads();
    if (kq == 0) {
        float mean = mred[0], var = mred[1] - mean * mean;
        float hv = (o - mean) * rsqrtf(var + 1e-5f) * n2g[j] + n2b[j];
        rowN[j] = hv;
        h[a * HH + j] = hv;
    }
    __syncthreads();
    // precompute next layer's conv input: hc = h_new @ WcN
    if (WcN) {
        float p = 0.0f;
        int k0 = kq * 32;
        #pragma unroll 8
        for (int kk = 0; kk < 32; ++kk) p = fmaf(rowN[k0 + kk], WcN[(k0 + kk) * HH + j], p);
        psum[kq][j] = p;
        __syncthreads();
        if (kq == 0) hc[a * HH + j] = psum[0][j] + psum[1][j] + psum[2][j] + psum[3][j];
    }
}

// Pool + heads + emb, 4 blocks x 512: blocks 0-2 = head k chain, block 3 = emb
__launch_bounds__(512)
__global__ void k_final4(const float* __restrict__ h,
                         const float* __restrict__ Wh1, const float* __restrict__ bh1,
                         const float* __restrict__ Wh2, const float* __restrict__ bh2,
                         const float* __restrict__ Wh3, const float* __restrict__ bh3,
                         const float* __restrict__ We, const float* __restrict__ be,
                         float* __restrict__ out) {
    __shared__ float gs[384];
    __shared__ float pm[4][HH], px[4][HH];
    __shared__ float psum[4][HH];
    __shared__ float t1s[HH];
    __shared__ float t2s[64];
    int tid = threadIdx.x, j = tid & 127, kq = tid >> 7, kb = blockIdx.x;
    // pool over 200 rows, 4 x 50 split
    {
        float sm = 0.0f, mx = -3.4e38f;
        for (int r = 0; r < 50; ++r) {
            float v = h[(kq * 50 + r) * HH + j];
            sm += v; mx = fmaxf(mx, v);
        }
        pm[kq][j] = sm; px[kq][j] = mx;
    }
    __syncthreads();
    if (tid < HH) {
        float s = pm[0][j] + pm[1][j] + pm[2][j] + pm[3][j];
        float m = fmaxf(fmaxf(px[0][j], px[1][j]), fmaxf(px[2][j], px[3][j]));
        gs[j] = s * (1.0f / NN); gs[HH + j] = m; gs[2 * HH + j] = s;
    }
    __syncthreads();
    if (kb < 3) {
        // t1 = gelu(g@Wh1[kb]+bh1): 128 outputs, dot 384, split 4x96
        float p = 0.0f;
        int i0 = kq * 96;
        #pragma unroll 8
        for (int ii = 0; ii < 96; ++ii) p = fmaf(gs[i0 + ii], Wh1[kb * 49152 + (i0 + ii) * 128 + j], p);
        psum[kq][j] = p;
        __syncthreads();
        if (tid < HH) t1s[j] = geluf(bh1[kb * 128 + j] + psum[0][j] + psum[1][j] + psum[2][j] + psum[3][j]);
        __syncthreads();
        // t2 = gelu(t1@Wh2[kb]+bh2): 64 outputs, dot 128, split 4x32
        if (tid < 256) {
            int o = tid & 63, sc = tid >> 6;
            float p2 = 0.0f;
            int i0b = sc * 32;
            #pragma unroll 8
            for (int ii = 0; ii < 32; ++ii) p2 = fmaf(t1s[i0b + ii], Wh2[kb * 8192 + (i0b + ii) * 64 + o], p2);
            psum[sc][o] = p2;
        }
        __syncthreads();
        if (tid < 64) t2s[tid] = geluf(bh2[kb * 64 + tid] + psum[0][tid] + psum[1][tid] + psum[2][tid] + psum[3][tid]);
        __syncthreads();
        if (tid < 64) {
            float v = t2s[tid] * Wh3[kb * 64 + tid];
            #pragma unroll
            for (int m = 32; m > 0; m >>= 1) v += __shfl_xor(v, m);
            if (tid == 0) {
                float acc = v + bh3[kb];
                float r;
                if (kb == 0)      r = softplusf(acc) + 1.0f;
                else if (kb == 1) r = 1.0f / (1.0f + expf(-acc));
                else              r = softplusf(acc);
                out[kb] = r;
            }
        }
    } else {
        // emb = g@We + be
        float p = 0.0f;
        int i0 = kq * 96;
        #pragma unroll 8
        for (int ii = 0; ii < 96; ++ii) p = fmaf(gs[i0 + ii], We[(i0 + ii) * 128 + j], p);
        psum[kq][j] = p;
        __syncthreads();
        if (tid < HH) out[3 + j] = be[j] + psum[0][j] + psum[1][j] + psum[2][j] + psum[3][j];
    }
}

// ---------------- launch ----------------

extern "C" void kernel_launch(void* const* d_in, const int* in_sizes, int n_in,
                              void* d_out, int out_size, void* d_ws, size_t ws_size,
                              hipStream_t stream) {
    const float* x      = (const float*)d_in[0];
    const int*   hedges = (const int*)d_in[1];
    const float* Wi     = (const float*)d_in[2];
    const float* bi     = (const float*)d_in[3];
    const float* lnig   = (const float*)d_in[4];
    const float* lnib   = (const float*)d_in[5];
    const float* Wc     = (const float*)d_in[6];
    const float* bc     = (const float*)d_in[7];
    const float* Wq     = (const float*)d_in[8];
    const float* bq     = (const float*)d_in[9];
    const float* Wk     = (const float*)d_in[10];
    const float* bk     = (const float*)d_in[11];
    const float* Wv     = (const float*)d_in[12];
    const float* bv     = (const float*)d_in[13];
    const float* Wo     = (const float*)d_in[14];
    const float* bo     = (const float*)d_in[15];
    const float* n1g    = (const float*)d_in[16];
    const float* n1b    = (const float*)d_in[17];
    const float* n2g    = (const float*)d_in[18];
    const float* n2b    = (const float*)d_in[19];
    const float* Wf1    = (const float*)d_in[20];
    const float* bf1    = (const float*)d_in[21];
    const float* Wf2    = (const float*)d_in[22];
    const float* bf2    = (const float*)d_in[23];
    const float* Wh1    = (const float*)d_in[24];
    const float* bh1    = (const float*)d_in[25];
    const float* Wh2    = (const float*)d_in[26];
    const float* bh2    = (const float*)d_in[27];
    const float* Wh3    = (const float*)d_in[28];
    const float* bh3    = (const float*)d_in[29];
    const float* We     = (const float*)d_in[30];
    const float* be     = (const float*)d_in[31];

    float* ws = (float*)d_ws;
    float* h   = ws;                         // 25600
    float* h1  = ws + 25600;                 // 25600
    float* hc  = ws + 51200;                 // 25600
    float* Q   = ws + 76800;                 // 25600
    float* K   = ws + 102400;                // 25600
    float* V   = ws + 128000;                // 25600
    int*   G   = (int*)(ws + 153600);        // 40000 ints
    unsigned long long* bmT = (unsigned long long*)(ws + 193600);  // 51200 u64 (8B-aligned)

    hipMemsetAsync(bmT, 0, (size_t)W64 * NN * sizeof(unsigned long long), stream);
    k_bitmap<<<(EE * SS) / 256, 256, 0, stream>>>(hedges, bmT);
    k_buildG2<<<NN, 256, 0, stream>>>(bmT, G);
    k_embed<<<NN, 512, 0, stream>>>(x, Wi, bi, lnig, lnib, Wc, h, hc);

    for (int l = 0; l < LL; ++l) {
        k_node1<<<NN, 512, 0, stream>>>(h, hc, G,
            bc + l * HH,
            Wq + l * HH * HH, bq + l * HH,
            Wk + l * HH * HH, bk + l * HH,
            Wv + l * HH * HH, bv + l * HH,
            n1g + l * HH, n1b + l * HH,
            h1, Q, K, V);
        const float* WcN = (l + 1 < LL) ? (Wc + (l + 1) * HH * HH) : nullptr;
        k_edgefused<<<NN, 512, 0, stream>>>(Q, K, V, hedges, bmT, h1,
            Wo + l * HH * HH, bo + l * HH,
            Wf1 + l * HH * FFD, bf1 + l * FFD,
            Wf2 + l * FFD * HH, bf2 + l * HH,
            n2g + l * HH, n2b + l * HH,
            WcN, h, hc);
    }

    k_final4<<<4, 512, 0, stream>>>(h, Wh1, bh1, Wh2, bh2, Wh3, bh3, We, be, (float*)d_out);
}